// Round 12
// baseline (982.658 us; speedup 1.0000x reference)
//
#include <hip/hip_runtime.h>
#include <hip/hip_bf16.h>
#include <hip/hip_fp16.h>

#define B_    8192
#define D_    1024
#define H_    4096
#define DOUT_ 1024
#define E_    8
#define MAXR  17408   // 16384 assignments + 8*128 padding

typedef float    f32x4 __attribute__((ext_vector_type(4)));
typedef _Float16 f16x8 __attribute__((ext_vector_type(8)));
typedef unsigned short u16;
typedef u16      u16x8 __attribute__((ext_vector_type(8)));
typedef u16      u16x4 __attribute__((ext_vector_type(4)));
typedef unsigned int u32;

__device__ __forceinline__ u16 f2h_bits(float f) {
  _Float16 h = (_Float16)f;
  return __builtin_bit_cast(u16, h);
}

// tanh-form gelu (max abs err vs erf-gelu ~3e-4; threshold margin 4x)
__device__ __forceinline__ float gelu_f(float v) {
  float z = 0.7978845608028654f * (v + 0.044715f * v * v * v);
  float ez = __expf(2.f * z);
  float th = 1.f - 2.f / (ez + 1.f);
  return 0.5f * v * (1.f + th);
}

// ---- workspace layout (bytes) ----
#define OFF_TOPI 512                       // int[16384]
#define OFF_TOPW (OFF_TOPI + 65536)        // float[16384]
#define OFF_ATOK (OFF_TOPW + 65536)        // int[17408]
#define OFF_WSL  (OFF_ATOK + 69632)        // float[17408]
#define OFF_XG   524288                    // u16[17408*1024] f16 (dead after gemm1)
#define OFF_W1T  (OFF_XG + 35651584)       // u16[8*4096*1024] f16 (dead after gemm1)
#define OFF_W2T  OFF_XG                    // u16[8*1024*4096] f16, ALIASES Xg+W1t
#define OFF_HB   (OFF_W1T + 67108864)      // u16[17408*4096] f16
// end = 245,891,072 bytes

__global__ void k_zero_out(float* __restrict__ out) {
  size_t i = (size_t)(blockIdx.x * 256 + threadIdx.x) * 4;
  *(f32x4*)&out[i] = (f32x4){0.f, 0.f, 0.f, 0.f};
}

__global__ void k_init(int* __restrict__ atok, float* __restrict__ wslot,
                       int* __restrict__ meta) {
  int i = blockIdx.x * 256 + threadIdx.x;
  if (i < MAXR) { atok[i] = 0; wslot[i] = 0.f; }
  if (blockIdx.x == 0 && threadIdx.x < 64) meta[threadIdx.x] = 0;
}

__global__ __launch_bounds__(256) void k_gate(
    const float* __restrict__ x, const float* __restrict__ Wg,
    const float* __restrict__ bg, int* __restrict__ counts,
    float* __restrict__ usage, int* __restrict__ topi, float* __restrict__ topw) {
  __shared__ float su[E_];
  if (threadIdx.x < E_) su[threadIdx.x] = 0.f;
  __syncthreads();
  const int lane = threadIdx.x & 63;
  const int b = blockIdx.x * 4 + (threadIdx.x >> 6);
  float p[E_] = {0.f,0.f,0.f,0.f,0.f,0.f,0.f,0.f};
  #pragma unroll
  for (int j = 0; j < 4; ++j) {
    int d = j * 256 + lane * 4;
    float4 xv = *(const float4*)&x[(size_t)b * D_ + d];
    const float* wr = &Wg[(size_t)d * E_];
    #pragma unroll
    for (int c = 0; c < 4; ++c) {
      float xc = reinterpret_cast<const float*>(&xv)[c];
      #pragma unroll
      for (int e = 0; e < E_; ++e) p[e] += xc * wr[c * E_ + e];
    }
  }
  #pragma unroll
  for (int off = 32; off >= 1; off >>= 1)
    #pragma unroll
    for (int e = 0; e < E_; ++e) p[e] += __shfl_xor(p[e], off, 64);
  float mx = -1e30f;
  #pragma unroll
  for (int e = 0; e < E_; ++e) { p[e] += bg[e]; mx = fmaxf(mx, p[e]); }
  int i0 = 0; float l0 = p[0];
  #pragma unroll
  for (int e = 1; e < E_; ++e) if (p[e] > l0) { l0 = p[e]; i0 = e; }
  int i1 = -1; float l1 = -1e30f;
  #pragma unroll
  for (int e = 0; e < E_; ++e) if (e != i0 && p[e] > l1) { l1 = p[e]; i1 = e; }
  float s = 0.f;
  #pragma unroll
  for (int e = 0; e < E_; ++e) { p[e] = expf(p[e] - mx); s += p[e]; }
  float inv = 1.f / s;
  if (lane == 0) {
    float e0 = expf(l0 - mx), e1 = expf(l1 - mx);
    float wsum = e0 + e1;
    topi[b * 2] = i0; topi[b * 2 + 1] = i1;
    topw[b * 2] = e0 / wsum; topw[b * 2 + 1] = e1 / wsum;
    atomicAdd(&counts[i0], 1);
    atomicAdd(&counts[i1], 1);
    #pragma unroll
    for (int e = 0; e < E_; ++e) atomicAdd(&su[e], p[e] * inv);
  }
  __syncthreads();
  if (threadIdx.x < E_) atomicAdd(&usage[threadIdx.x], su[threadIdx.x]);
}

__global__ void k_scan_aux(const int* __restrict__ counts, int* __restrict__ offsets,
                           const float* __restrict__ usage, float* __restrict__ auxp) {
  if (threadIdx.x == 0) {
    int off = 0;
    for (int e = 0; e < E_; ++e) { offsets[e] = off; off += (counts[e] + 127) & ~127; }
    offsets[E_] = off;
    float aux = 0.f;
    const float lu = logf(1.0f / (float)E_);
    for (int e = 0; e < E_; ++e) {
      float u = usage[e] * (1.0f / (float)B_);
      aux += u * lu - logf(u) * (1.0f / (float)E_);
    }
    *auxp = aux;
  }
}

__global__ void k_scatter(const int* __restrict__ topi, const float* __restrict__ topw,
                          const int* __restrict__ offsets, int* __restrict__ cursors,
                          int* __restrict__ atok, float* __restrict__ wslot) {
  int b = blockIdx.x * 256 + threadIdx.x;
  if (b >= B_) return;
  #pragma unroll
  for (int k = 0; k < 2; ++k) {
    int e = topi[b * 2 + k];
    int pos = atomicAdd(&cursors[e], 1);
    int slot = offsets[e] + pos;
    atok[slot] = b;
    wslot[slot] = topw[b * 2 + k];
  }
}

__global__ __launch_bounds__(256) void k_gather(const float* __restrict__ x,
                                                const int* __restrict__ atok,
                                                u16* __restrict__ Xg) {
  int slot = blockIdx.x;
  int tok = atok[slot];
  int c = threadIdx.x * 4;
  float4 v = *(const float4*)&x[(size_t)tok * D_ + c];
  const float* vf = reinterpret_cast<const float*>(&v);
  u16x4 o;
  o.x = f2h_bits(vf[0]); o.y = f2h_bits(vf[1]);
  o.z = f2h_bits(vf[2]); o.w = f2h_bits(vf[3]);
  *(u16x4*)&Xg[(size_t)slot * D_ + c] = o;
}

// convert + transpose: src [E][K][N] fp32  ->  dst [E][N][K] f16. 64x64 tiles.
__global__ __launch_bounds__(256) void k_cvt_t(const float* __restrict__ src,
                                               u16* __restrict__ dst, int K, int N) {
  const int e = blockIdx.z;
  const int kt = blockIdx.x * 64;
  const int nt = blockIdx.y * 64;
  __shared__ u16 t[64][68];
  const float* s = src + (size_t)e * K * N;
  u16* d = dst + (size_t)e * N * K;
  const int tr = threadIdx.x >> 4;
  const int tc = threadIdx.x & 15;
  #pragma unroll
  for (int i = 0; i < 4; ++i) {
    int k = tr + i * 16;
    float4 v = *(const float4*)&s[(size_t)(kt + k) * N + nt + tc * 4];
    t[k][tc*4+0] = f2h_bits(v.x); t[k][tc*4+1] = f2h_bits(v.y);
    t[k][tc*4+2] = f2h_bits(v.z); t[k][tc*4+3] = f2h_bits(v.w);
  }
  __syncthreads();
  #pragma unroll
  for (int i = 0; i < 4; ++i) {
    int n = tr + i * 16;
    u16x4 o;
    o.x = t[tc*4+0][n]; o.y = t[tc*4+1][n];
    o.z = t[tc*4+2][n]; o.w = t[tc*4+3][n];
    *(u16x4*)&d[(size_t)(nt + n) * K + kt + tc * 4] = o;
  }
}

#define GLDS(g, l) __builtin_amdgcn_global_load_lds( \
    (const u32 __attribute__((address_space(1)))*)(g), \
    (u32 __attribute__((address_space(3)))*)(l), 16, 0, 0)

// ==== m97 core: 128x128 tile, BK=64, SINGLE-buffer 32KB LDS, 4 waves (2Mx2N),
// 2-barrier loop, latency hidden by 5 blocks/CU cross-block TLP. ====
// LDS: SM[16384] u16; A@0 (128x64), B@8192. Row = 64 u16 = 128B.
// XOR swizzle pair (8 x 16B chunks/row): LDS[row][c] = src[row][c ^ (row&7)]
//   stage: lane l of segment (8 rows) loads src chunk (l&7)^((l>>3)&7), writes
//          linear dest; read: chunk' = (ks*4+hi) ^ (row&7) -> 2-way banks (free).
// 16 segments of 8 rows; seg = wid*4+i; segment = 512 u16 (1KB).
#define STG(LDK, kk, Aoff, Boff) do { \
  const int rl_ = lane >> 3; \
  const int sc_ = ((lane & 7) ^ rl_) * 8; \
  _Pragma("unroll") \
  for (int i = 0; i < 4; ++i) { \
    int seg = wid * 4 + i; \
    GLDS(Ap + (size_t)(seg * 8 + rl_) * (LDK) + (kk) + sc_, SM + (Aoff) + seg * 512); \
    GLDS(Bp + (size_t)(seg * 8 + rl_) * (LDK) + (kk) + sc_, SM + (Boff) + seg * 512); \
  } } while (0)

// wave-tile 64x64: per step 2 ks x (4 af + 4 bf ds_read_b128 + 16 MFMA) = 32 MFMA
#define CMP(Aoff, Boff) do { \
  const int r15_ = lane & 15; \
  const int hi_ = lane >> 4; \
  _Pragma("unroll") \
  for (int ks = 0; ks < 2; ++ks) { \
    f16x8 af[4], bf[4]; \
    _Pragma("unroll") \
    for (int m = 0; m < 4; ++m) { \
      int row = wr * 64 + m * 16 + r15_; \
      af[m] = *(const f16x8*)&SM[(Aoff) + row * 64 + (((ks * 4 + hi_) ^ (row & 7)) * 8)]; \
    } \
    _Pragma("unroll") \
    for (int n = 0; n < 4; ++n) { \
      int row = wc * 64 + n * 16 + r15_; \
      bf[n] = *(const f16x8*)&SM[(Boff) + row * 64 + (((ks * 4 + hi_) ^ (row & 7)) * 8)]; \
    } \
    _Pragma("unroll") \
    for (int m = 0; m < 4; ++m) \
      _Pragma("unroll") \
      for (int n = 0; n < 4; ++n) \
        acc[m][n] = __builtin_amdgcn_mfma_f32_16x16x32_f16(af[m], bf[n], acc[m][n], 0, 0, 0); \
  } } while (0)

// GEMM1: Hb[row][n] = gelu( Xg[row][:] @ W1t[e][n][:]^T + b1[e][n] )  (f16)
// DENSE grid 136x32 (mt-major, R10-proven). 16 K-steps of BK=64.
__global__ __launch_bounds__(256) void k_gemm1(
    const u16* __restrict__ Xg, const u16* __restrict__ W1t,
    const float* __restrict__ b1, const int* __restrict__ offsets,
    u16* __restrict__ Hb) {
  const int L = blockIdx.x;
  const int mtile = L >> 5;
  const int nt = L & 31;
  const int row0 = mtile * 128;
  if (row0 >= offsets[E_]) return;
  int e = 0;
  #pragma unroll
  for (int i = 1; i < E_; ++i) e = (row0 >= offsets[i]) ? i : e;
  const int n0 = nt * 128;
  const int tid = threadIdx.x, lane = tid & 63, wid = tid >> 6;
  const int wr = wid >> 1, wc = wid & 1;
  __shared__ __align__(16) u16 SM[16384];
  f32x4 acc[4][4] = {};
  const u16* Ap = Xg + (size_t)row0 * D_;
  const u16* Bp = W1t + (size_t)e * H_ * D_ + (size_t)n0 * D_;

  for (int t = 0; t < 16; ++t) {
    STG(D_, t * 64, 0, 8192);
    __syncthreads();
    CMP(0, 8192);
    __syncthreads();
  }
  // epilogue: bias+gelu -> LDS (64 x 136, 272B rows, 16B-aligned) -> 16B stores
  const int rhi = (lane >> 4) * 4, cix = lane & 15;
  float bv[4];
  #pragma unroll
  for (int n = 0; n < 4; ++n) bv[n] = b1[e * H_ + n0 + wc * 64 + n * 16 + cix];
  #pragma unroll
  for (int r = 0; r < 2; ++r) {
    if (wr == r) {
      #pragma unroll
      for (int m = 0; m < 4; ++m)
        #pragma unroll
        for (int n = 0; n < 4; ++n)
          #pragma unroll
          for (int j = 0; j < 4; ++j)
            SM[(m * 16 + rhi + j) * 136 + wc * 64 + n * 16 + cix] =
                f2h_bits(gelu_f(acc[m][n][j] + bv[n]));
    }
    __syncthreads();
    {
      const int rl = tid >> 2, co = (tid & 3) * 32;
      u16* dst = &Hb[(size_t)(row0 + r * 64 + rl) * H_ + n0 + co];
      const u16* srcp = &SM[rl * 136 + co];
      #pragma unroll
      for (int qq = 0; qq < 4; ++qq)
        *(u16x8*)(dst + qq * 8) = *(const u16x8*)(srcp + qq * 8);
    }
    __syncthreads();
  }
}

// GEMM2: out[tok][n] += wslot * ( Hb[row][:] @ W2t[e][n][:]^T + b2[e][n] )
// DENSE grid 136x8, full K=4096 (64 steps of BK=64), atomic combine.
__global__ __launch_bounds__(256) void k_gemm2(
    const u16* __restrict__ Hb, const u16* __restrict__ W2t,
    const float* __restrict__ b2, const int* __restrict__ offsets,
    const int* __restrict__ atok, const float* __restrict__ wslot,
    float* __restrict__ out) {
  const int L = blockIdx.x;
  const int mtile = L >> 3;
  const int nt = L & 7;
  const int row0 = mtile * 128;
  if (row0 >= offsets[E_]) return;
  int e = 0;
  #pragma unroll
  for (int i = 1; i < E_; ++i) e = (row0 >= offsets[i]) ? i : e;
  const int n0 = nt * 128;
  const int tid = threadIdx.x, lane = tid & 63, wid = tid >> 6;
  const int wr = wid >> 1, wc = wid & 1;
  __shared__ __align__(16) u16 SM[16384];
  f32x4 acc[4][4] = {};
  const u16* Ap = Hb + (size_t)row0 * H_;
  const u16* Bp = W2t + (size_t)e * DOUT_ * H_ + (size_t)n0 * H_;

  for (int t = 0; t < 64; ++t) {
    STG(H_, t * 64, 0, 8192);
    __syncthreads();
    CMP(0, 8192);
    __syncthreads();
  }
  const int rhi = (lane >> 4) * 4, cix = lane & 15;
  float bv[4];
  #pragma unroll
  for (int n = 0; n < 4; ++n) bv[n] = b2[e * DOUT_ + n0 + wc * 64 + n * 16 + cix];
  #pragma unroll
  for (int m = 0; m < 4; ++m) {
    #pragma unroll
    for (int j = 0; j < 4; ++j) {
      int slot = row0 + wr * 64 + m * 16 + rhi + j;
      float w = wslot[slot];
      if (w == 0.f) continue;   // padding slot
      int tok = atok[slot];
      float* orow = out + (size_t)tok * DOUT_ + n0;
      #pragma unroll
      for (int n = 0; n < 4; ++n) {
        int lc = wc * 64 + n * 16 + cix;
        atomicAdd(&orow[lc], w * (acc[m][n][j] + bv[n]));
      }
    }
  }
}

extern "C" void kernel_launch(void* const* d_in, const int* in_sizes, int n_in,
                              void* d_out, int out_size, void* d_ws, size_t ws_size,
                              hipStream_t stream) {
  const float* x  = (const float*)d_in[0];
  const float* Wg = (const float*)d_in[1];
  const float* bg = (const float*)d_in[2];
  const float* W1 = (const float*)d_in[3];
  const float* b1 = (const float*)d_in[4];
  const float* W2 = (const float*)d_in[5];
  const float* b2 = (const float*)d_in[6];
  float* out = (float*)d_out;

  char* ws = (char*)d_ws;
  int*   counts  = (int*)(ws + 0);
  int*   cursors = (int*)(ws + 32);
  int*   offsets = (int*)(ws + 64);
  float* usage   = (float*)(ws + 128);
  int*   topi    = (int*)(ws + OFF_TOPI);
  float* topw    = (float*)(ws + OFF_TOPW);
  int*   atok    = (int*)(ws + OFF_ATOK);
  float* wslot   = (float*)(ws + OFF_WSL);
  u16*   Xg      = (u16*)(ws + OFF_XG);
  u16*   W1t     = (u16*)(ws + OFF_W1T);
  u16*   W2t     = (u16*)(ws + OFF_W2T);
  u16*   Hb      = (u16*)(ws + OFF_HB);

  k_zero_out<<<B_ * DOUT_ / 1024, 256, 0, stream>>>(out);
  k_init<<<(MAXR + 255) / 256, 256, 0, stream>>>(atok, wslot, (int*)ws);
  k_gate<<<B_ / 4, 256, 0, stream>>>(x, Wg, bg, counts, usage, topi, topw);
  k_scan_aux<<<1, 64, 0, stream>>>(counts, offsets, usage, out + (size_t)B_ * DOUT_);
  k_scatter<<<B_ / 256, 256, 0, stream>>>(topi, topw, offsets, cursors, atok, wslot);
  k_gather<<<MAXR, 256, 0, stream>>>(x, atok, Xg);
  k_cvt_t<<<dim3(D_ / 64, H_ / 64, E_), 256, 0, stream>>>(W1, W1t, D_, H_);
  k_gemm1<<<(MAXR / 128) * 32, 256, 0, stream>>>(Xg, W1t, b1, offsets, Hb);
  k_cvt_t<<<dim3(H_ / 64, DOUT_ / 64, E_), 256, 0, stream>>>(W2, W2t, H_, DOUT_);
  k_gemm2<<<(MAXR / 128) * 8, 256, 0, stream>>>(Hb, W2t, b2, offsets, atok, wslot, out);
}

// Round 13
// 960.091 us; speedup vs baseline: 1.0235x; 1.0235x over previous
//
#include <hip/hip_runtime.h>
#include <hip/hip_bf16.h>
#include <hip/hip_fp16.h>

#define B_    8192
#define D_    1024
#define H_    4096
#define DOUT_ 1024
#define E_    8
#define MAXR  17408   // 16384 assignments + 8*128 padding
#define NT256 72      // max 256-row tiles

typedef float    f32x4 __attribute__((ext_vector_type(4)));
typedef _Float16 f16x8 __attribute__((ext_vector_type(8)));
typedef unsigned short u16;
typedef u16      u16x8 __attribute__((ext_vector_type(8)));
typedef u16      u16x4 __attribute__((ext_vector_type(4)));
typedef unsigned int u32;

__device__ __forceinline__ u16 f2h_bits(float f) {
  _Float16 h = (_Float16)f;
  return __builtin_bit_cast(u16, h);
}

// tanh-form gelu (max abs err vs erf-gelu ~3e-4; threshold margin 4x)
__device__ __forceinline__ float gelu_f(float v) {
  float z = 0.7978845608028654f * (v + 0.044715f * v * v * v);
  float ez = __expf(2.f * z);
  float th = 1.f - 2.f / (ez + 1.f);
  return 0.5f * v * (1.f + th);
}

// ---- workspace layout (bytes) ----
#define OFF_TOPI 512                       // int[16384]
#define OFF_TOPW (OFF_TOPI + 65536)        // float[16384]
#define OFF_ATOK (OFF_TOPW + 65536)        // int[17408]
#define OFF_WSL  (OFF_ATOK + 69632)        // float[17408]
#define OFF_TMAP 280064                    // int[NT256] packed (e<<20|row0)
#define OFF_XG   524288                    // u16[17408*1024] f16 (dead after gemm1)
#define OFF_W1T  (OFF_XG + 35651584)       // u16[8*4096*1024] f16 (dead after gemm1)
#define OFF_W2T  OFF_XG                    // u16[8*1024*4096] f16, ALIASES Xg+W1t
#define OFF_HB   (OFF_W1T + 67108864)      // u16[17408*4096] f16
// end = 245,891,072 bytes

__global__ void k_zero_out(float* __restrict__ out) {
  size_t i = (size_t)(blockIdx.x * 256 + threadIdx.x) * 4;
  *(f32x4*)&out[i] = (f32x4){0.f, 0.f, 0.f, 0.f};
}

__global__ void k_init(int* __restrict__ atok, float* __restrict__ wslot,
                       int* __restrict__ meta) {
  int i = blockIdx.x * 256 + threadIdx.x;
  if (i < MAXR) { atok[i] = 0; wslot[i] = 0.f; }
  if (blockIdx.x == 0 && threadIdx.x < 64) meta[threadIdx.x] = 0;
}

__global__ __launch_bounds__(256) void k_gate(
    const float* __restrict__ x, const float* __restrict__ Wg,
    const float* __restrict__ bg, int* __restrict__ counts,
    float* __restrict__ usage, int* __restrict__ topi, float* __restrict__ topw) {
  __shared__ float su[E_];
  if (threadIdx.x < E_) su[threadIdx.x] = 0.f;
  __syncthreads();
  const int lane = threadIdx.x & 63;
  const int b = blockIdx.x * 4 + (threadIdx.x >> 6);
  float p[E_] = {0.f,0.f,0.f,0.f,0.f,0.f,0.f,0.f};
  #pragma unroll
  for (int j = 0; j < 4; ++j) {
    int d = j * 256 + lane * 4;
    float4 xv = *(const float4*)&x[(size_t)b * D_ + d];
    const float* wr = &Wg[(size_t)d * E_];
    #pragma unroll
    for (int c = 0; c < 4; ++c) {
      float xc = reinterpret_cast<const float*>(&xv)[c];
      #pragma unroll
      for (int e = 0; e < E_; ++e) p[e] += xc * wr[c * E_ + e];
    }
  }
  #pragma unroll
  for (int off = 32; off >= 1; off >>= 1)
    #pragma unroll
    for (int e = 0; e < E_; ++e) p[e] += __shfl_xor(p[e], off, 64);
  float mx = -1e30f;
  #pragma unroll
  for (int e = 0; e < E_; ++e) { p[e] += bg[e]; mx = fmaxf(mx, p[e]); }
  int i0 = 0; float l0 = p[0];
  #pragma unroll
  for (int e = 1; e < E_; ++e) if (p[e] > l0) { l0 = p[e]; i0 = e; }
  int i1 = -1; float l1 = -1e30f;
  #pragma unroll
  for (int e = 0; e < E_; ++e) if (e != i0 && p[e] > l1) { l1 = p[e]; i1 = e; }
  float s = 0.f;
  #pragma unroll
  for (int e = 0; e < E_; ++e) { p[e] = expf(p[e] - mx); s += p[e]; }
  float inv = 1.f / s;
  if (lane == 0) {
    float e0 = expf(l0 - mx), e1 = expf(l1 - mx);
    float wsum = e0 + e1;
    topi[b * 2] = i0; topi[b * 2 + 1] = i1;
    topw[b * 2] = e0 / wsum; topw[b * 2 + 1] = e1 / wsum;
    atomicAdd(&counts[i0], 1);
    atomicAdd(&counts[i1], 1);
    #pragma unroll
    for (int e = 0; e < E_; ++e) atomicAdd(&su[e], p[e] * inv);
  }
  __syncthreads();
  if (threadIdx.x < E_) atomicAdd(&usage[threadIdx.x], su[threadIdx.x]);
}

__global__ void k_scan_aux(const int* __restrict__ counts, int* __restrict__ offsets,
                           const float* __restrict__ usage, float* __restrict__ auxp,
                           int* __restrict__ tmap) {
  if (threadIdx.x == 0) {
    int off = 0;
    for (int e = 0; e < E_; ++e) { offsets[e] = off; off += (counts[e] + 127) & ~127; }
    offsets[E_] = off;
    int nT = 0;
    for (int e = 0; e < E_; ++e) {
      int roff = offsets[e], pn = offsets[e + 1] - roff;
      for (int r0 = 0; r0 < pn; r0 += 256)
        tmap[nT++] = (e << 20) | (roff + r0);
    }
    for (int t = nT; t < NT256; ++t) tmap[t] = -1;
    float aux = 0.f;
    const float lu = logf(1.0f / (float)E_);
    for (int e = 0; e < E_; ++e) {
      float u = usage[e] * (1.0f / (float)B_);
      aux += u * lu - logf(u) * (1.0f / (float)E_);
    }
    *auxp = aux;
  }
}

__global__ void k_scatter(const int* __restrict__ topi, const float* __restrict__ topw,
                          const int* __restrict__ offsets, int* __restrict__ cursors,
                          int* __restrict__ atok, float* __restrict__ wslot) {
  int b = blockIdx.x * 256 + threadIdx.x;
  if (b >= B_) return;
  #pragma unroll
  for (int k = 0; k < 2; ++k) {
    int e = topi[b * 2 + k];
    int pos = atomicAdd(&cursors[e], 1);
    int slot = offsets[e] + pos;
    atok[slot] = b;
    wslot[slot] = topw[b * 2 + k];
  }
}

__global__ __launch_bounds__(256) void k_gather(const float* __restrict__ x,
                                                const int* __restrict__ atok,
                                                u16* __restrict__ Xg) {
  int slot = blockIdx.x;
  int tok = atok[slot];
  int c = threadIdx.x * 4;
  float4 v = *(const float4*)&x[(size_t)tok * D_ + c];
  const float* vf = reinterpret_cast<const float*>(&v);
  u16x4 o;
  o.x = f2h_bits(vf[0]); o.y = f2h_bits(vf[1]);
  o.z = f2h_bits(vf[2]); o.w = f2h_bits(vf[3]);
  *(u16x4*)&Xg[(size_t)slot * D_ + c] = o;
}

// convert + transpose: src [E][K][N] fp32  ->  dst [E][N][K] f16. 64x64 tiles.
__global__ __launch_bounds__(256) void k_cvt_t(const float* __restrict__ src,
                                               u16* __restrict__ dst, int K, int N) {
  const int e = blockIdx.z;
  const int kt = blockIdx.x * 64;
  const int nt = blockIdx.y * 64;
  __shared__ u16 t[64][68];
  const float* s = src + (size_t)e * K * N;
  u16* d = dst + (size_t)e * N * K;
  const int tr = threadIdx.x >> 4;
  const int tc = threadIdx.x & 15;
  #pragma unroll
  for (int i = 0; i < 4; ++i) {
    int k = tr + i * 16;
    float4 v = *(const float4*)&s[(size_t)(kt + k) * N + nt + tc * 4];
    t[k][tc*4+0] = f2h_bits(v.x); t[k][tc*4+1] = f2h_bits(v.y);
    t[k][tc*4+2] = f2h_bits(v.z); t[k][tc*4+3] = f2h_bits(v.w);
  }
  __syncthreads();
  #pragma unroll
  for (int i = 0; i < 4; ++i) {
    int n = tr + i * 16;
    u16x4 o;
    o.x = t[tc*4+0][n]; o.y = t[tc*4+1][n];
    o.z = t[tc*4+2][n]; o.w = t[tc*4+3][n];
    *(u16x4*)&d[(size_t)(nt + n) * K + kt + tc * 4] = o;
  }
}

#define GLDS(g, l) __builtin_amdgcn_global_load_lds( \
    (const u32 __attribute__((address_space(1)))*)(g), \
    (u32 __attribute__((address_space(3)))*)(l), 16, 0, 0)

#define VMWAIT(N) asm volatile("s_waitcnt vmcnt(" #N ")" ::: "memory")
#define BARRIER() do { __builtin_amdgcn_s_barrier(); \
                       asm volatile("" ::: "memory"); } while (0)

// ==== 256x256 tile, BK=64 split in two K-halves, 128KB LDS dbuf, 8 waves ====
// LDS u16 map per buffer b (base bb = b*32768):
//   Akh0 @ bb+0, Bkh0 @ bb+8192, Akh1 @ bb+16384, Bkh1 @ bb+24576  (8192 u16 ea)
// K-half block = 256 rows x 32 u16 (64B rows), XOR swizzle (R9/R11-proven pair):
//   LDS[row][chunk] = src[row][chunk ^ ((r15^(r15>>2))&3)], r15 = row&15.
// Stage one A+B K-half pair: 4 gload_lds per thread (512 thr x 16B x 2 = 16KB ea).
#define STGP(LDK, kk, bb, kh) do { \
  const int r_ = lane >> 2; \
  const int sc_ = ((lane & 3) ^ ((r_ ^ (r_ >> 2)) & 3)) * 8; \
  _Pragma("unroll") \
  for (int j = 0; j < 2; ++j) { \
    int seg = wid * 2 + j;                       /* 0..15, wave-uniform */ \
    int rowA = seg * 16 + r_; if (rowA > Alim) rowA = Alim; \
    GLDS(Ap + (size_t)rowA * (LDK) + (kk) + (kh) * 32 + sc_, \
         SM + (bb) + (kh) * 16384 + seg * 512); \
    GLDS(Bp + (size_t)(seg * 16 + r_) * (LDK) + (kk) + (kh) * 32 + sc_, \
         SM + (bb) + (kh) * 16384 + 8192 + seg * 512); \
  } } while (0)

// one K-half compute: 12 ds_read_b128 + 32 MFMA (8m x 4n), setprio-wrapped
#define CMPH(bb, kh) do { \
  const int r15_ = lane & 15; \
  const int co_ = (((lane >> 4) ^ ((r15_ ^ (r15_ >> 2)) & 3)) * 8); \
  f16x8 af[8], bf[4]; \
  _Pragma("unroll") \
  for (int m = 0; m < 8; ++m) \
    af[m] = *(const f16x8*)&SM[(bb) + (kh) * 16384 + (wr * 128 + m * 16 + r15_) * 32 + co_]; \
  _Pragma("unroll") \
  for (int n = 0; n < 4; ++n) \
    bf[n] = *(const f16x8*)&SM[(bb) + (kh) * 16384 + 8192 + (wc * 64 + n * 16 + r15_) * 32 + co_]; \
  __builtin_amdgcn_s_setprio(1); \
  _Pragma("unroll") \
  for (int m = 0; m < 8; ++m) \
    _Pragma("unroll") \
    for (int n = 0; n < 4; ++n) \
      acc[m][n] = __builtin_amdgcn_mfma_f32_16x16x32_f16(af[m], bf[n], acc[m][n], 0, 0, 0); \
  __builtin_amdgcn_s_setprio(0); \
  } while (0)

// steady-state phase: stage one half-pair of tile t+1, wait oldest pair, compute
#define PHASE(LDK, kk1, nb, cb, kh) do { \
  STGP(LDK, kk1, nb, kh); \
  VMWAIT(8); \
  BARRIER(); \
  CMPH(cb, kh); \
  BARRIER(); \
} while (0)

// GEMM1: Hb[row][n] = gelu( Xg[row][:] @ W1t[e][n][:]^T + b1[e][n] )  (f16)
__global__ __launch_bounds__(512, 2) void k_gemm1(
    const u16* __restrict__ Xg, const u16* __restrict__ W1t,
    const float* __restrict__ b1, const int* __restrict__ offsets,
    const int* __restrict__ tmap, u16* __restrict__ Hb) {
  const int packed = tmap[blockIdx.x >> 4];
  if (packed < 0) return;
  const int e = packed >> 20;
  const int row0g = packed & 0xFFFFF;
  const int rend = offsets[e + 1];
  const int nt = blockIdx.x & 15;
  const int n0 = nt * 256;
  const int tid = threadIdx.x, lane = tid & 63, wid = tid >> 6;
  const int wr = wid >> 2, wc = wid & 3;     // 2M x 4N waves, wave-tile 128x64
  const int Alim = (MAXR - 1) - row0g;
  __shared__ __align__(16) u16 SM[65536];    // 128KB
  f32x4 acc[8][4] = {};
  const u16* Ap = Xg + (size_t)row0g * D_;
  const u16* Bp = W1t + (size_t)e * H_ * D_ + (size_t)n0 * D_;

  STGP(D_, 0, 0, 0);
  STGP(D_, 0, 0, 1);                         // tile 0 fully issued (8 loads)
  for (int t = 0; t < 15; ++t) {             // NT=16 k-tiles, last peeled
    const int cb = (t & 1) << 15;            // *32768
    const int nb = cb ^ 32768;
    PHASE(D_, (t + 1) * 64, nb, cb, 0);
    PHASE(D_, (t + 1) * 64, nb, cb, 1);
  }
  {                                          // t = 15, no staging
    const int cb = 32768;
    VMWAIT(4); BARRIER(); CMPH(cb, 0); BARRIER();
    VMWAIT(0); BARRIER(); CMPH(cb, 1); BARRIER();
  }
  // epilogue: bias+gelu -> LDS (64 x 264 u16 rows, 16B-aligned) -> 16B stores
  const int rhi = (lane >> 4) * 4, cix = lane & 15;
  float bv[4];
  #pragma unroll
  for (int n = 0; n < 4; ++n) bv[n] = b1[e * H_ + n0 + wc * 64 + n * 16 + cix];
  #pragma unroll
  for (int rr = 0; rr < 4; ++rr) {
    if (wr == (rr >> 1)) {
      const int mb = (rr & 1) * 4;
      #pragma unroll
      for (int m = 0; m < 4; ++m)
        #pragma unroll
        for (int n = 0; n < 4; ++n)
          #pragma unroll
          for (int j = 0; j < 4; ++j)
            SM[(m * 16 + rhi + j) * 264 + wc * 64 + n * 16 + cix] =
                f2h_bits(gelu_f(acc[mb + m][n][j] + bv[n]));
    }
    __syncthreads();
    {
      const int rl = tid >> 3, co = (tid & 7) * 32;
      const int gr = row0g + rr * 64 + rl;
      if (gr < rend) {
        u16* dst = &Hb[(size_t)gr * H_ + n0 + co];
        const u16* sp = &SM[rl * 264 + co];
        #pragma unroll
        for (int qq = 0; qq < 4; ++qq)
          *(u16x8*)(dst + qq * 8) = *(const u16x8*)(sp + qq * 8);
      }
    }
    __syncthreads();
  }
}

// GEMM2: out[tok][n] += wslot * ( Hb[row][:] @ W2t[e][n][:]^T + b2[e][n] )
// 256x256 tile, K-split=2 (blockIdx.y), 32 k-tiles each, atomic combine.
__global__ __launch_bounds__(512, 2) void k_gemm2(
    const u16* __restrict__ Hb, const u16* __restrict__ W2t,
    const float* __restrict__ b2, const int* __restrict__ offsets,
    const int* __restrict__ tmap, const int* __restrict__ atok,
    const float* __restrict__ wslot, float* __restrict__ out) {
  const int packed = tmap[blockIdx.x >> 2];
  if (packed < 0) return;
  const int e = packed >> 20;
  const int row0g = packed & 0xFFFFF;
  const int rend = offsets[e + 1];
  const int nt = blockIdx.x & 3;
  const int n0 = nt * 256;
  const int kbase = blockIdx.y * 2048;
  const int tid = threadIdx.x, lane = tid & 63, wid = tid >> 6;
  const int wr = wid >> 2, wc = wid & 3;
  const int Alim = (MAXR - 1) - row0g;
  __shared__ __align__(16) u16 SM[65536];
  f32x4 acc[8][4] = {};
  const u16* Ap = Hb + (size_t)row0g * H_ + kbase;
  const u16* Bp = W2t + (size_t)e * DOUT_ * H_ + (size_t)n0 * H_ + kbase;

  STGP(H_, 0, 0, 0);
  STGP(H_, 0, 0, 1);
  for (int t = 0; t < 31; ++t) {             // NT=32 k-tiles, last peeled
    const int cb = (t & 1) << 15;
    const int nb = cb ^ 32768;
    PHASE(H_, (t + 1) * 64, nb, cb, 0);
    PHASE(H_, (t + 1) * 64, nb, cb, 1);
  }
  {
    const int cb = 32768;
    VMWAIT(4); BARRIER(); CMPH(cb, 0); BARRIER();
    VMWAIT(0); BARRIER(); CMPH(cb, 1); BARRIER();
  }
  const int rhi = (lane >> 4) * 4, cix = lane & 15;
  const int first = (kbase == 0);
  float bv[4];
  #pragma unroll
  for (int n = 0; n < 4; ++n) bv[n] = b2[e * DOUT_ + n0 + wc * 64 + n * 16 + cix];
  #pragma unroll
  for (int m = 0; m < 8; ++m) {
    #pragma unroll
    for (int j = 0; j < 4; ++j) {
      int slot = row0g + wr * 128 + m * 16 + rhi + j;
      if (slot >= rend) continue;        // overhang into next expert's region
      float w = wslot[slot];
      if (w == 0.f) continue;            // padding slot
      int tok = atok[slot];
      float* orow = out + (size_t)tok * DOUT_ + n0;
      #pragma unroll
      for (int n = 0; n < 4; ++n) {
        int lc = wc * 64 + n * 16 + cix;
        float v = first ? w * (acc[m][n][j] + bv[n]) : w * acc[m][n][j];
        atomicAdd(&orow[lc], v);
      }
    }
  }
}

extern "C" void kernel_launch(void* const* d_in, const int* in_sizes, int n_in,
                              void* d_out, int out_size, void* d_ws, size_t ws_size,
                              hipStream_t stream) {
  const float* x  = (const float*)d_in[0];
  const float* Wg = (const float*)d_in[1];
  const float* bg = (const float*)d_in[2];
  const float* W1 = (const float*)d_in[3];
  const float* b1 = (const float*)d_in[4];
  const float* W2 = (const float*)d_in[5];
  const float* b2 = (const float*)d_in[6];
  float* out = (float*)d_out;

  char* ws = (char*)d_ws;
  int*   counts  = (int*)(ws + 0);
  int*   cursors = (int*)(ws + 32);
  int*   offsets = (int*)(ws + 64);
  float* usage   = (float*)(ws + 128);
  int*   topi    = (int*)(ws + OFF_TOPI);
  float* topw    = (float*)(ws + OFF_TOPW);
  int*   atok    = (int*)(ws + OFF_ATOK);
  float* wslot   = (float*)(ws + OFF_WSL);
  int*   tmap    = (int*)(ws + OFF_TMAP);
  u16*   Xg      = (u16*)(ws + OFF_XG);
  u16*   W1t     = (u16*)(ws + OFF_W1T);
  u16*   W2t     = (u16*)(ws + OFF_W2T);
  u16*   Hb      = (u16*)(ws + OFF_HB);

  k_zero_out<<<B_ * DOUT_ / 1024, 256, 0, stream>>>(out);
  k_init<<<(MAXR + 255) / 256, 256, 0, stream>>>(atok, wslot, (int*)ws);
  k_gate<<<B_ / 4, 256, 0, stream>>>(x, Wg, bg, counts, usage, topi, topw);
  k_scan_aux<<<1, 64, 0, stream>>>(counts, offsets, usage, out + (size_t)B_ * DOUT_, tmap);
  k_scatter<<<B_ / 256, 256, 0, stream>>>(topi, topw, offsets, cursors, atok, wslot);
  k_gather<<<MAXR, 256, 0, stream>>>(x, atok, Xg);
  k_cvt_t<<<dim3(D_ / 64, H_ / 64, E_), 256, 0, stream>>>(W1, W1t, D_, H_);
  k_gemm1<<<NT256 * 16, 512, 0, stream>>>(Xg, W1t, b1, offsets, tmap, Hb);
  k_cvt_t<<<dim3(H_ / 64, DOUT_ / 64, E_), 256, 0, stream>>>(W2, W2t, H_, DOUT_);
  k_gemm2<<<dim3(NT256 * 4, 2), 512, 0, stream>>>(Hb, W2t, b2, offsets, tmap, atok, wslot, out);
}

// Round 14
// 836.046 us; speedup vs baseline: 1.1754x; 1.1484x over previous
//
#include <hip/hip_runtime.h>
#include <hip/hip_bf16.h>
#include <hip/hip_fp16.h>

#define B_    8192
#define D_    1024
#define H_    4096
#define DOUT_ 1024
#define E_    8
#define MAXR  17408   // 16384 assignments + 8*128 padding

typedef float    f32x4 __attribute__((ext_vector_type(4)));
typedef _Float16 f16x8 __attribute__((ext_vector_type(8)));
typedef unsigned short u16;
typedef u16      u16x8 __attribute__((ext_vector_type(8)));
typedef u16      u16x4 __attribute__((ext_vector_type(4)));
typedef unsigned int u32;

__device__ __forceinline__ u16 f2h_bits(float f) {
  _Float16 h = (_Float16)f;
  return __builtin_bit_cast(u16, h);
}

// tanh-form gelu (max abs err vs erf-gelu ~3e-4; threshold margin 4x)
__device__ __forceinline__ float gelu_f(float v) {
  float z = 0.7978845608028654f * (v + 0.044715f * v * v * v);
  float ez = __expf(2.f * z);
  float th = 1.f - 2.f / (ez + 1.f);
  return 0.5f * v * (1.f + th);
}

// ---- workspace layout (bytes) ----
#define OFF_TOPI 512                       // int[16384]
#define OFF_TOPW (OFF_TOPI + 65536)        // float[16384]
#define OFF_ATOK (OFF_TOPW + 65536)        // int[17408]
#define OFF_WSL  (OFF_ATOK + 69632)        // float[17408]
#define OFF_XG   524288                    // u16[17408*1024] f16 (dead after gemm1)
#define OFF_W1T  (OFF_XG + 35651584)       // u16[8*4096*1024] f16 (dead after gemm1)
#define OFF_W2T  OFF_XG                    // u16[8*1024*4096] f16, ALIASES Xg+W1t
#define OFF_HB   (OFF_W1T + 67108864)      // u16[17408*4096] f16
// end = 245,891,072 bytes

__global__ void k_zero_out(float* __restrict__ out) {
  size_t i = (size_t)(blockIdx.x * 256 + threadIdx.x) * 4;
  *(f32x4*)&out[i] = (f32x4){0.f, 0.f, 0.f, 0.f};
}

__global__ void k_init(int* __restrict__ atok, float* __restrict__ wslot,
                       int* __restrict__ meta) {
  int i = blockIdx.x * 256 + threadIdx.x;
  if (i < MAXR) { atok[i] = 0; wslot[i] = 0.f; }
  if (blockIdx.x == 0 && threadIdx.x < 64) meta[threadIdx.x] = 0;
}

__global__ __launch_bounds__(256) void k_gate(
    const float* __restrict__ x, const float* __restrict__ Wg,
    const float* __restrict__ bg, int* __restrict__ counts,
    float* __restrict__ usage, int* __restrict__ topi, float* __restrict__ topw) {
  __shared__ float su[E_];
  if (threadIdx.x < E_) su[threadIdx.x] = 0.f;
  __syncthreads();
  const int lane = threadIdx.x & 63;
  const int b = blockIdx.x * 4 + (threadIdx.x >> 6);
  float p[E_] = {0.f,0.f,0.f,0.f,0.f,0.f,0.f,0.f};
  #pragma unroll
  for (int j = 0; j < 4; ++j) {
    int d = j * 256 + lane * 4;
    float4 xv = *(const float4*)&x[(size_t)b * D_ + d];
    const float* wr = &Wg[(size_t)d * E_];
    #pragma unroll
    for (int c = 0; c < 4; ++c) {
      float xc = reinterpret_cast<const float*>(&xv)[c];
      #pragma unroll
      for (int e = 0; e < E_; ++e) p[e] += xc * wr[c * E_ + e];
    }
  }
  #pragma unroll
  for (int off = 32; off >= 1; off >>= 1)
    #pragma unroll
    for (int e = 0; e < E_; ++e) p[e] += __shfl_xor(p[e], off, 64);
  float mx = -1e30f;
  #pragma unroll
  for (int e = 0; e < E_; ++e) { p[e] += bg[e]; mx = fmaxf(mx, p[e]); }
  int i0 = 0; float l0 = p[0];
  #pragma unroll
  for (int e = 1; e < E_; ++e) if (p[e] > l0) { l0 = p[e]; i0 = e; }
  int i1 = -1; float l1 = -1e30f;
  #pragma unroll
  for (int e = 0; e < E_; ++e) if (e != i0 && p[e] > l1) { l1 = p[e]; i1 = e; }
  float s = 0.f;
  #pragma unroll
  for (int e = 0; e < E_; ++e) { p[e] = expf(p[e] - mx); s += p[e]; }
  float inv = 1.f / s;
  if (lane == 0) {
    float e0 = expf(l0 - mx), e1 = expf(l1 - mx);
    float wsum = e0 + e1;
    topi[b * 2] = i0; topi[b * 2 + 1] = i1;
    topw[b * 2] = e0 / wsum; topw[b * 2 + 1] = e1 / wsum;
    atomicAdd(&counts[i0], 1);
    atomicAdd(&counts[i1], 1);
    #pragma unroll
    for (int e = 0; e < E_; ++e) atomicAdd(&su[e], p[e] * inv);
  }
  __syncthreads();
  if (threadIdx.x < E_) atomicAdd(&usage[threadIdx.x], su[threadIdx.x]);
}

__global__ void k_scan_aux(const int* __restrict__ counts, int* __restrict__ offsets,
                           const float* __restrict__ usage, float* __restrict__ auxp) {
  if (threadIdx.x == 0) {
    int off = 0;
    for (int e = 0; e < E_; ++e) { offsets[e] = off; off += (counts[e] + 127) & ~127; }
    offsets[E_] = off;
    float aux = 0.f;
    const float lu = logf(1.0f / (float)E_);
    for (int e = 0; e < E_; ++e) {
      float u = usage[e] * (1.0f / (float)B_);
      aux += u * lu - logf(u) * (1.0f / (float)E_);
    }
    *auxp = aux;
  }
}

__global__ void k_scatter(const int* __restrict__ topi, const float* __restrict__ topw,
                          const int* __restrict__ offsets, int* __restrict__ cursors,
                          int* __restrict__ atok, float* __restrict__ wslot) {
  int b = blockIdx.x * 256 + threadIdx.x;
  if (b >= B_) return;
  #pragma unroll
  for (int k = 0; k < 2; ++k) {
    int e = topi[b * 2 + k];
    int pos = atomicAdd(&cursors[e], 1);
    int slot = offsets[e] + pos;
    atok[slot] = b;
    wslot[slot] = topw[b * 2 + k];
  }
}

__global__ __launch_bounds__(256) void k_gather(const float* __restrict__ x,
                                                const int* __restrict__ atok,
                                                u16* __restrict__ Xg) {
  int slot = blockIdx.x;
  int tok = atok[slot];
  int c = threadIdx.x * 4;
  float4 v = *(const float4*)&x[(size_t)tok * D_ + c];
  const float* vf = reinterpret_cast<const float*>(&v);
  u16x4 o;
  o.x = f2h_bits(vf[0]); o.y = f2h_bits(vf[1]);
  o.z = f2h_bits(vf[2]); o.w = f2h_bits(vf[3]);
  *(u16x4*)&Xg[(size_t)slot * D_ + c] = o;
}

// convert + transpose: src [E][K][N] fp32  ->  dst [E][N][K] f16. 64x64 tiles.
__global__ __launch_bounds__(256) void k_cvt_t(const float* __restrict__ src,
                                               u16* __restrict__ dst, int K, int N) {
  const int e = blockIdx.z;
  const int kt = blockIdx.x * 64;
  const int nt = blockIdx.y * 64;
  __shared__ u16 t[64][68];
  const float* s = src + (size_t)e * K * N;
  u16* d = dst + (size_t)e * N * K;
  const int tr = threadIdx.x >> 4;
  const int tc = threadIdx.x & 15;
  #pragma unroll
  for (int i = 0; i < 4; ++i) {
    int k = tr + i * 16;
    float4 v = *(const float4*)&s[(size_t)(kt + k) * N + nt + tc * 4];
    t[k][tc*4+0] = f2h_bits(v.x); t[k][tc*4+1] = f2h_bits(v.y);
    t[k][tc*4+2] = f2h_bits(v.z); t[k][tc*4+3] = f2h_bits(v.w);
  }
  __syncthreads();
  #pragma unroll
  for (int i = 0; i < 4; ++i) {
    int n = tr + i * 16;
    u16x4 o;
    o.x = t[tc*4+0][n]; o.y = t[tc*4+1][n];
    o.z = t[tc*4+2][n]; o.w = t[tc*4+3][n];
    *(u16x4*)&d[(size_t)(nt + n) * K + kt + tc * 4] = o;
  }
}

#define GLDS(g, l) __builtin_amdgcn_global_load_lds( \
    (const u32 __attribute__((address_space(1)))*)(g), \
    (u32 __attribute__((address_space(3)))*)(l), 16, 0, 0)

#define VMWAIT(N) asm volatile("s_waitcnt vmcnt(" #N ")" ::: "memory")
#define BARRIER() do { __builtin_amdgcn_s_barrier(); \
                       asm volatile("" ::: "memory"); } while (0)

// ==== 128x128 tile, BK=32, RING-3 LDS (48KB -> 3 blocks/CU), fine phases ====
// Ring buf bases (u16): 0, 8192, 16384. Per buf: A @ +0 (128x32 u16), B @ +4096.
// XOR source-swizzle pair (R11-proven): LDS[row][c] = src[row][c ^ ((r15^(r15>>2))&3)]
// Stage tile kt -> base sb: 4 gload_lds per thread (A:2, B:2).
#define NXT(x) ((x) == 16384 ? 0 : (x) + 8192)

#define STG3(LDK, kt, sb) do { \
  const int r_ = lane >> 2; \
  const int sc_ = ((lane & 3) ^ ((r_ ^ (r_ >> 2)) & 3)) * 8; \
  _Pragma("unroll") \
  for (int j = 0; j < 2; ++j) { \
    int rw = j * 64 + wid * 16 + r_; \
    GLDS(Ap + (size_t)rw * (LDK) + (kt) * 32 + sc_, SM + (sb) + j * 2048 + wid * 512); \
    GLDS(Bp + (size_t)rw * (LDK) + (kt) * 32 + sc_, SM + (sb) + 4096 + j * 2048 + wid * 512); \
  } } while (0)

// frag reads for one k-tile (8 ds_read_b128/wave), issued BEFORE the barrier
#define RD_FR(rb_) do { \
  const int r15_ = lane & 15; \
  const int co_ = (((lane >> 4) ^ ((r15_ ^ (r15_ >> 2)) & 3)) * 8); \
  _Pragma("unroll") \
  for (int mi = 0; mi < 4; ++mi) \
    af[mi] = *(const f16x8*)&SM[(rb_) + (wr * 64 + mi * 16 + r15_) * 32 + co_]; \
  _Pragma("unroll") \
  for (int n = 0; n < 4; ++n) \
    bf[n] = *(const f16x8*)&SM[(rb_) + 4096 + (wc * 64 + n * 16 + r15_) * 32 + co_]; \
} while (0)

// 16 MFMA cluster, setprio-wrapped (T5)
#define MM16() do { \
  __builtin_amdgcn_s_setprio(1); \
  _Pragma("unroll") \
  for (int mi = 0; mi < 4; ++mi) \
    _Pragma("unroll") \
    for (int n = 0; n < 4; ++n) \
      acc[mi][n] = __builtin_amdgcn_mfma_f32_16x16x32_f16(af[mi], bf[n], acc[mi][n], 0, 0, 0); \
  __builtin_amdgcn_s_setprio(0); \
} while (0)

// Ring-3 pipelined K-loop. Per phase t: reads(tile t) ; stage(tile t+2) ;
// barrier ; MFMA ; VMWAIT(4) [drain tile t+1, keep t+2 in flight] ; barrier.
#define KLOOP(LDK, NT) do { \
  int rb = 0, wb = 16384; \
  STG3(LDK, 0, 0); \
  STG3(LDK, 1, 8192); \
  VMWAIT(4); \
  BARRIER(); \
  for (int t = 0; t < (NT); ++t) { \
    RD_FR(rb); \
    if (t + 2 < (NT)) STG3(LDK, t + 2, wb); \
    BARRIER(); \
    MM16(); \
    if (t + 2 < (NT)) VMWAIT(4); \
    else if (t + 1 < (NT)) VMWAIT(0); \
    BARRIER(); \
    rb = NXT(rb); wb = NXT(wb); \
  } \
} while (0)

// GEMM1: Hb[row][n] = gelu( Xg[row][:] @ W1t[e][n][:]^T + b1[e][n] )  (f16)
// DENSE grid 136x32 (mt-major, R10/R12-proven). NT=32 k-tiles of BK=32.
__global__ __launch_bounds__(256, 3) void k_gemm1(
    const u16* __restrict__ Xg, const u16* __restrict__ W1t,
    const float* __restrict__ b1, const int* __restrict__ offsets,
    u16* __restrict__ Hb) {
  const int L = blockIdx.x;
  const int mtile = L >> 5;
  const int nt = L & 31;
  const int row0 = mtile * 128;
  if (row0 >= offsets[E_]) return;
  int e = 0;
  #pragma unroll
  for (int i = 1; i < E_; ++i) e = (row0 >= offsets[i]) ? i : e;
  const int n0 = nt * 128;
  const int tid = threadIdx.x, lane = tid & 63, wid = tid >> 6;
  const int wr = wid >> 1, wc = wid & 1;
  __shared__ __align__(16) u16 SM[24576];   // 48 KB ring-3
  f32x4 acc[4][4] = {};
  f16x8 af[4], bf[4];
  const u16* Ap = Xg + (size_t)row0 * D_;
  const u16* Bp = W1t + (size_t)e * H_ * D_ + (size_t)n0 * D_;

  KLOOP(D_, 32);

  // epilogue: bias+gelu -> LDS (64 x 136, 272B rows, 16B-aligned) -> 16B stores
  const int rhi = (lane >> 4) * 4, cix = lane & 15;
  float bv[4];
  #pragma unroll
  for (int n = 0; n < 4; ++n) bv[n] = b1[e * H_ + n0 + wc * 64 + n * 16 + cix];
  #pragma unroll
  for (int r = 0; r < 2; ++r) {
    if (wr == r) {
      #pragma unroll
      for (int m = 0; m < 4; ++m)
        #pragma unroll
        for (int n = 0; n < 4; ++n)
          #pragma unroll
          for (int j = 0; j < 4; ++j)
            SM[(m * 16 + rhi + j) * 136 + wc * 64 + n * 16 + cix] =
                f2h_bits(gelu_f(acc[m][n][j] + bv[n]));
    }
    __syncthreads();
    {
      const int rl = tid >> 2, co = (tid & 3) * 32;
      u16* dst = &Hb[(size_t)(row0 + r * 64 + rl) * H_ + n0 + co];
      const u16* srcp = &SM[rl * 136 + co];
      #pragma unroll
      for (int qq = 0; qq < 4; ++qq)
        *(u16x8*)(dst + qq * 8) = *(const u16x8*)(srcp + qq * 8);
    }
    __syncthreads();
  }
}

// GEMM2: out[tok][n] += wslot * ( Hb[row][:] @ W2t[e][n][:]^T + b2[e][n] )
// DENSE grid 136x8 x Ksplit2; NT=64 k-tiles each; atomic combine.
__global__ __launch_bounds__(256, 3) void k_gemm2(
    const u16* __restrict__ Hb, const u16* __restrict__ W2t,
    const float* __restrict__ b2, const int* __restrict__ offsets,
    const int* __restrict__ atok, const float* __restrict__ wslot,
    float* __restrict__ out) {
  const int L = blockIdx.x;
  const int mtile = L >> 3;
  const int nt = L & 7;
  const int row0 = mtile * 128;
  if (row0 >= offsets[E_]) return;
  int e = 0;
  #pragma unroll
  for (int i = 1; i < E_; ++i) e = (row0 >= offsets[i]) ? i : e;
  const int n0 = nt * 128;
  const int kbase = blockIdx.y * 2048;
  const int tid = threadIdx.x, lane = tid & 63, wid = tid >> 6;
  const int wr = wid >> 1, wc = wid & 1;
  __shared__ __align__(16) u16 SM[24576];
  f32x4 acc[4][4] = {};
  f16x8 af[4], bf[4];
  const u16* Ap = Hb + (size_t)row0 * H_ + kbase;
  const u16* Bp = W2t + (size_t)e * DOUT_ * H_ + (size_t)n0 * H_ + kbase;

  KLOOP(H_, 64);

  const int rhi = (lane >> 4) * 4, cix = lane & 15;
  const int first = (kbase == 0);
  float bv[4];
  #pragma unroll
  for (int n = 0; n < 4; ++n) bv[n] = b2[e * DOUT_ + n0 + wc * 64 + n * 16 + cix];
  #pragma unroll
  for (int m = 0; m < 4; ++m) {
    #pragma unroll
    for (int j = 0; j < 4; ++j) {
      int slot = row0 + wr * 64 + m * 16 + rhi + j;
      float w = wslot[slot];
      if (w == 0.f) continue;   // padding slot
      int tok = atok[slot];
      float* orow = out + (size_t)tok * DOUT_ + n0;
      #pragma unroll
      for (int n = 0; n < 4; ++n) {
        int lc = wc * 64 + n * 16 + cix;
        float v = first ? w * (acc[m][n][j] + bv[n]) : w * acc[m][n][j];
        atomicAdd(&orow[lc], v);
      }
    }
  }
}

extern "C" void kernel_launch(void* const* d_in, const int* in_sizes, int n_in,
                              void* d_out, int out_size, void* d_ws, size_t ws_size,
                              hipStream_t stream) {
  const float* x  = (const float*)d_in[0];
  const float* Wg = (const float*)d_in[1];
  const float* bg = (const float*)d_in[2];
  const float* W1 = (const float*)d_in[3];
  const float* b1 = (const float*)d_in[4];
  const float* W2 = (const float*)d_in[5];
  const float* b2 = (const float*)d_in[6];
  float* out = (float*)d_out;

  char* ws = (char*)d_ws;
  int*   counts  = (int*)(ws + 0);
  int*   cursors = (int*)(ws + 32);
  int*   offsets = (int*)(ws + 64);
  float* usage   = (float*)(ws + 128);
  int*   topi    = (int*)(ws + OFF_TOPI);
  float* topw    = (float*)(ws + OFF_TOPW);
  int*   atok    = (int*)(ws + OFF_ATOK);
  float* wslot   = (float*)(ws + OFF_WSL);
  u16*   Xg      = (u16*)(ws + OFF_XG);
  u16*   W1t     = (u16*)(ws + OFF_W1T);
  u16*   W2t     = (u16*)(ws + OFF_W2T);
  u16*   Hb      = (u16*)(ws + OFF_HB);

  k_zero_out<<<B_ * DOUT_ / 1024, 256, 0, stream>>>(out);
  k_init<<<(MAXR + 255) / 256, 256, 0, stream>>>(atok, wslot, (int*)ws);
  k_gate<<<B_ / 4, 256, 0, stream>>>(x, Wg, bg, counts, usage, topi, topw);
  k_scan_aux<<<1, 64, 0, stream>>>(counts, offsets, usage, out + (size_t)B_ * DOUT_);
  k_scatter<<<B_ / 256, 256, 0, stream>>>(topi, topw, offsets, cursors, atok, wslot);
  k_gather<<<MAXR, 256, 0, stream>>>(x, atok, Xg);
  k_cvt_t<<<dim3(D_ / 64, H_ / 64, E_), 256, 0, stream>>>(W1, W1t, D_, H_);
  k_gemm1<<<(MAXR / 128) * 32, 256, 0, stream>>>(Xg, W1t, b1, offsets, Hb);
  k_cvt_t<<<dim3(H_ / 64, DOUT_ / 64, E_), 256, 0, stream>>>(W2, W2t, H_, DOUT_);
  k_gemm2<<<dim3((MAXR / 128) * 8, 2), 256, 0, stream>>>(Hb, W2t, b2, offsets, atok, wslot, out);
}

// Round 15
// 818.417 us; speedup vs baseline: 1.2007x; 1.0215x over previous
//
#include <hip/hip_runtime.h>
#include <hip/hip_bf16.h>
#include <hip/hip_fp16.h>

#define B_    8192
#define D_    1024
#define H_    4096
#define DOUT_ 1024
#define E_    8
#define MAXR  17408   // 16384 assignments + 8*128 padding

typedef float    f32x4 __attribute__((ext_vector_type(4)));
typedef _Float16 f16x8 __attribute__((ext_vector_type(8)));
typedef unsigned short u16;
typedef u16      u16x8 __attribute__((ext_vector_type(8)));
typedef u16      u16x4 __attribute__((ext_vector_type(4)));
typedef unsigned int u32;

__device__ __forceinline__ u16 f2h_bits(float f) {
  _Float16 h = (_Float16)f;
  return __builtin_bit_cast(u16, h);
}

// tanh-form gelu (max abs err vs erf-gelu ~3e-4; threshold margin 4x)
__device__ __forceinline__ float gelu_f(float v) {
  float z = 0.7978845608028654f * (v + 0.044715f * v * v * v);
  float ez = __expf(2.f * z);
  float th = 1.f - 2.f / (ez + 1.f);
  return 0.5f * v * (1.f + th);
}

// ---- workspace layout (bytes) ----
#define OFF_TOPI 512                       // int[16384]
#define OFF_TOPW (OFF_TOPI + 65536)        // float[16384]
#define OFF_ATOK (OFF_TOPW + 65536)        // int[17408]
#define OFF_WSL  (OFF_ATOK + 69632)        // float[17408]
#define OFF_XG   524288                    // u16[17408*1024] f16 (dead after gemm1)
#define OFF_W1T  (OFF_XG + 35651584)       // u16[8*4096*1024] f16 (dead after gemm1)
#define OFF_W2T  OFF_XG                    // u16[8*1024*4096] f16, ALIASES Xg+W1t
#define OFF_HB   (OFF_W1T + 67108864)      // u16[17408*4096] f16
// end = 245,891,072 bytes

__global__ void k_zero_out(float* __restrict__ out) {
  size_t i = (size_t)(blockIdx.x * 256 + threadIdx.x) * 4;
  *(f32x4*)&out[i] = (f32x4){0.f, 0.f, 0.f, 0.f};
}

__global__ void k_init(int* __restrict__ atok, float* __restrict__ wslot,
                       int* __restrict__ meta) {
  int i = blockIdx.x * 256 + threadIdx.x;
  if (i < MAXR) { atok[i] = 0; wslot[i] = 0.f; }
  if (blockIdx.x == 0 && threadIdx.x < 64) meta[threadIdx.x] = 0;
}

__global__ __launch_bounds__(256) void k_gate(
    const float* __restrict__ x, const float* __restrict__ Wg,
    const float* __restrict__ bg, int* __restrict__ counts,
    float* __restrict__ usage, int* __restrict__ topi, float* __restrict__ topw) {
  __shared__ float su[E_];
  if (threadIdx.x < E_) su[threadIdx.x] = 0.f;
  __syncthreads();
  const int lane = threadIdx.x & 63;
  const int b = blockIdx.x * 4 + (threadIdx.x >> 6);
  float p[E_] = {0.f,0.f,0.f,0.f,0.f,0.f,0.f,0.f};
  #pragma unroll
  for (int j = 0; j < 4; ++j) {
    int d = j * 256 + lane * 4;
    float4 xv = *(const float4*)&x[(size_t)b * D_ + d];
    const float* wr = &Wg[(size_t)d * E_];
    #pragma unroll
    for (int c = 0; c < 4; ++c) {
      float xc = reinterpret_cast<const float*>(&xv)[c];
      #pragma unroll
      for (int e = 0; e < E_; ++e) p[e] += xc * wr[c * E_ + e];
    }
  }
  #pragma unroll
  for (int off = 32; off >= 1; off >>= 1)
    #pragma unroll
    for (int e = 0; e < E_; ++e) p[e] += __shfl_xor(p[e], off, 64);
  float mx = -1e30f;
  #pragma unroll
  for (int e = 0; e < E_; ++e) { p[e] += bg[e]; mx = fmaxf(mx, p[e]); }
  int i0 = 0; float l0 = p[0];
  #pragma unroll
  for (int e = 1; e < E_; ++e) if (p[e] > l0) { l0 = p[e]; i0 = e; }
  int i1 = -1; float l1 = -1e30f;
  #pragma unroll
  for (int e = 0; e < E_; ++e) if (e != i0 && p[e] > l1) { l1 = p[e]; i1 = e; }
  float s = 0.f;
  #pragma unroll
  for (int e = 0; e < E_; ++e) { p[e] = expf(p[e] - mx); s += p[e]; }
  float inv = 1.f / s;
  if (lane == 0) {
    float e0 = expf(l0 - mx), e1 = expf(l1 - mx);
    float wsum = e0 + e1;
    topi[b * 2] = i0; topi[b * 2 + 1] = i1;
    topw[b * 2] = e0 / wsum; topw[b * 2 + 1] = e1 / wsum;
    atomicAdd(&counts[i0], 1);
    atomicAdd(&counts[i1], 1);
    #pragma unroll
    for (int e = 0; e < E_; ++e) atomicAdd(&su[e], p[e] * inv);
  }
  __syncthreads();
  if (threadIdx.x < E_) atomicAdd(&usage[threadIdx.x], su[threadIdx.x]);
}

__global__ void k_scan_aux(const int* __restrict__ counts, int* __restrict__ offsets,
                           const float* __restrict__ usage, float* __restrict__ auxp) {
  if (threadIdx.x == 0) {
    int off = 0;
    for (int e = 0; e < E_; ++e) { offsets[e] = off; off += (counts[e] + 127) & ~127; }
    offsets[E_] = off;
    float aux = 0.f;
    const float lu = logf(1.0f / (float)E_);
    for (int e = 0; e < E_; ++e) {
      float u = usage[e] * (1.0f / (float)B_);
      aux += u * lu - logf(u) * (1.0f / (float)E_);
    }
    *auxp = aux;
  }
}

__global__ void k_scatter(const int* __restrict__ topi, const float* __restrict__ topw,
                          const int* __restrict__ offsets, int* __restrict__ cursors,
                          int* __restrict__ atok, float* __restrict__ wslot) {
  int b = blockIdx.x * 256 + threadIdx.x;
  if (b >= B_) return;
  #pragma unroll
  for (int k = 0; k < 2; ++k) {
    int e = topi[b * 2 + k];
    int pos = atomicAdd(&cursors[e], 1);
    int slot = offsets[e] + pos;
    atok[slot] = b;
    wslot[slot] = topw[b * 2 + k];
  }
}

__global__ __launch_bounds__(256) void k_gather(const float* __restrict__ x,
                                                const int* __restrict__ atok,
                                                u16* __restrict__ Xg) {
  int slot = blockIdx.x;
  int tok = atok[slot];
  int c = threadIdx.x * 4;
  float4 v = *(const float4*)&x[(size_t)tok * D_ + c];
  const float* vf = reinterpret_cast<const float*>(&v);
  u16x4 o;
  o.x = f2h_bits(vf[0]); o.y = f2h_bits(vf[1]);
  o.z = f2h_bits(vf[2]); o.w = f2h_bits(vf[3]);
  *(u16x4*)&Xg[(size_t)slot * D_ + c] = o;
}

// convert + transpose: src [E][K][N] fp32  ->  dst [E][N][K] f16. 64x64 tiles.
__global__ __launch_bounds__(256) void k_cvt_t(const float* __restrict__ src,
                                               u16* __restrict__ dst, int K, int N) {
  const int e = blockIdx.z;
  const int kt = blockIdx.x * 64;
  const int nt = blockIdx.y * 64;
  __shared__ u16 t[64][68];
  const float* s = src + (size_t)e * K * N;
  u16* d = dst + (size_t)e * N * K;
  const int tr = threadIdx.x >> 4;
  const int tc = threadIdx.x & 15;
  #pragma unroll
  for (int i = 0; i < 4; ++i) {
    int k = tr + i * 16;
    float4 v = *(const float4*)&s[(size_t)(kt + k) * N + nt + tc * 4];
    t[k][tc*4+0] = f2h_bits(v.x); t[k][tc*4+1] = f2h_bits(v.y);
    t[k][tc*4+2] = f2h_bits(v.z); t[k][tc*4+3] = f2h_bits(v.w);
  }
  __syncthreads();
  #pragma unroll
  for (int i = 0; i < 4; ++i) {
    int n = tr + i * 16;
    u16x4 o;
    o.x = t[tc*4+0][n]; o.y = t[tc*4+1][n];
    o.z = t[tc*4+2][n]; o.w = t[tc*4+3][n];
    *(u16x4*)&d[(size_t)(nt + n) * K + kt + tc * 4] = o;
  }
}

#define GLDS(g, l) __builtin_amdgcn_global_load_lds( \
    (const u32 __attribute__((address_space(1)))*)(g), \
    (u32 __attribute__((address_space(3)))*)(l), 16, 0, 0)

#define VMWAIT(N) asm volatile("s_waitcnt vmcnt(" #N ")" ::: "memory")
#define BARRIER() do { __builtin_amdgcn_s_barrier(); \
                       asm volatile("" ::: "memory"); } while (0)

// ==== 128(M)x256(N) tile, BK=32, RING-3 LDS (72KB -> 2 blocks/CU), 8 waves ====
// Ring buffer (u16): bases 0, 12288, 24576; per buf: A @ +0 (128x32), B @ +4096
// (256x32). XOR source-swizzle pair (R11/R14-proven):
//   LDS[row][c] = src[row][c ^ ((r15^(r15>>2))&3)]  (16B chunks, r15=row&15)
// Stage tile kt: 3 gload_lds/thread (A:1, B:2). 512 threads, wid 0..7.
#define NXT(x) ((x) == 24576 ? 0 : (x) + 12288)

#define STG3(LDK, kt, sb) do { \
  const int r_ = lane >> 2; \
  const int sc_ = ((lane & 3) ^ ((r_ ^ (r_ >> 2)) & 3)) * 8; \
  { \
    int rw = wid * 16 + r_; \
    GLDS(Ap + (size_t)rw * (LDK) + (kt) * 32 + sc_, SM + (sb) + wid * 512); \
  } \
  _Pragma("unroll") \
  for (int j = 0; j < 2; ++j) { \
    int seg = wid * 2 + j; \
    GLDS(Bp + (size_t)(seg * 16 + r_) * (LDK) + (kt) * 32 + sc_, \
         SM + (sb) + 4096 + seg * 512); \
  } } while (0)

// frag reads for one k-tile (8 ds_read_b128/wave), issued BEFORE the barrier
#define RD_FR(rb_) do { \
  const int r15_ = lane & 15; \
  const int co_ = (((lane >> 4) ^ ((r15_ ^ (r15_ >> 2)) & 3)) * 8); \
  _Pragma("unroll") \
  for (int mi = 0; mi < 4; ++mi) \
    af[mi] = *(const f16x8*)&SM[(rb_) + (wr * 64 + mi * 16 + r15_) * 32 + co_]; \
  _Pragma("unroll") \
  for (int n = 0; n < 4; ++n) \
    bf[n] = *(const f16x8*)&SM[(rb_) + 4096 + (wc * 64 + n * 16 + r15_) * 32 + co_]; \
} while (0)

// 16 MFMA cluster, setprio-wrapped (T5)
#define MM16() do { \
  __builtin_amdgcn_s_setprio(1); \
  _Pragma("unroll") \
  for (int mi = 0; mi < 4; ++mi) \
    _Pragma("unroll") \
    for (int n = 0; n < 4; ++n) \
      acc[mi][n] = __builtin_amdgcn_mfma_f32_16x16x32_f16(af[mi], bf[n], acc[mi][n], 0, 0, 0); \
  __builtin_amdgcn_s_setprio(0); \
} while (0)

// Ring-3 pipelined K-loop (R14-proven ledger, 3 loads/tile). Per phase t:
// reads(t) ; stage(t+2) ; barrier ; MFMA ; VMWAIT(3) [drain t+1, keep t+2] ; barrier.
#define KLOOP(LDK, NT) do { \
  int rb = 0, wb = 24576; \
  STG3(LDK, 0, 0); \
  STG3(LDK, 1, 12288); \
  VMWAIT(3); \
  BARRIER(); \
  for (int t = 0; t < (NT); ++t) { \
    RD_FR(rb); \
    if (t + 2 < (NT)) STG3(LDK, t + 2, wb); \
    BARRIER(); \
    MM16(); \
    if (t + 2 < (NT)) VMWAIT(3); \
    else if (t + 1 < (NT)) VMWAIT(0); \
    BARRIER(); \
    rb = NXT(rb); wb = NXT(wb); \
  } \
} while (0)

// GEMM1: Hb[row][n] = gelu( Xg[row][:] @ W1t[e][n][:]^T + b1[e][n] )  (f16)
// DENSE grid 136 mtiles x 16 ntiles (mt-major); NT=32 k-tiles of BK=32.
__global__ __launch_bounds__(512, 4) void k_gemm1(
    const u16* __restrict__ Xg, const u16* __restrict__ W1t,
    const float* __restrict__ b1, const int* __restrict__ offsets,
    u16* __restrict__ Hb) {
  const int L = blockIdx.x;
  const int mtile = L >> 4;
  const int nt = L & 15;
  const int row0 = mtile * 128;
  if (row0 >= offsets[E_]) return;
  int e = 0;
  #pragma unroll
  for (int i = 1; i < E_; ++i) e = (row0 >= offsets[i]) ? i : e;
  const int n0 = nt * 256;
  const int tid = threadIdx.x, lane = tid & 63, wid = tid >> 6;
  const int wr = wid >> 2, wc = wid & 3;    // 2M x 4N waves, wave-tile 64x64
  __shared__ __align__(16) u16 SM[36864];   // 72 KB ring-3
  f32x4 acc[4][4] = {};
  f16x8 af[4], bf[4];
  const u16* Ap = Xg + (size_t)row0 * D_;
  const u16* Bp = W1t + (size_t)e * H_ * D_ + (size_t)n0 * D_;

  KLOOP(D_, 32);

  // epilogue: bias+gelu -> LDS (64 x 264 u16, 528B rows = 16B-aligned) -> 16B st
  const int rhi = (lane >> 4) * 4, cix = lane & 15;
  float bv[4];
  #pragma unroll
  for (int n = 0; n < 4; ++n) bv[n] = b1[e * H_ + n0 + wc * 64 + n * 16 + cix];
  #pragma unroll
  for (int r = 0; r < 2; ++r) {
    if (wr == r) {
      #pragma unroll
      for (int m = 0; m < 4; ++m)
        #pragma unroll
        for (int n = 0; n < 4; ++n)
          #pragma unroll
          for (int j = 0; j < 4; ++j)
            SM[(m * 16 + rhi + j) * 264 + wc * 64 + n * 16 + cix] =
                f2h_bits(gelu_f(acc[m][n][j] + bv[n]));
    }
    __syncthreads();
    {
      const int rl = tid >> 3, co = (tid & 7) * 32;
      u16* dst = &Hb[(size_t)(row0 + r * 64 + rl) * H_ + n0 + co];
      const u16* srcp = &SM[rl * 264 + co];
      #pragma unroll
      for (int qq = 0; qq < 4; ++qq)
        *(u16x8*)(dst + qq * 8) = *(const u16x8*)(srcp + qq * 8);
    }
    __syncthreads();
  }
}

// GEMM2: out[tok][n] += wslot * ( Hb[row][:] @ W2t[e][n][:]^T + b2[e][n] )
// DENSE grid 136 mtiles x 4 ntiles x Ksplit2; NT=64 k-tiles; atomic combine.
__global__ __launch_bounds__(512, 4) void k_gemm2(
    const u16* __restrict__ Hb, const u16* __restrict__ W2t,
    const float* __restrict__ b2, const int* __restrict__ offsets,
    const int* __restrict__ atok, const float* __restrict__ wslot,
    float* __restrict__ out) {
  const int L = blockIdx.x;
  const int mtile = L >> 2;
  const int nt = L & 3;
  const int row0 = mtile * 128;
  if (row0 >= offsets[E_]) return;
  int e = 0;
  #pragma unroll
  for (int i = 1; i < E_; ++i) e = (row0 >= offsets[i]) ? i : e;
  const int n0 = nt * 256;
  const int kbase = blockIdx.y * 2048;
  const int tid = threadIdx.x, lane = tid & 63, wid = tid >> 6;
  const int wr = wid >> 2, wc = wid & 3;
  __shared__ __align__(16) u16 SM[36864];
  f32x4 acc[4][4] = {};
  f16x8 af[4], bf[4];
  const u16* Ap = Hb + (size_t)row0 * H_ + kbase;
  const u16* Bp = W2t + (size_t)e * DOUT_ * H_ + (size_t)n0 * H_ + kbase;

  KLOOP(H_, 64);

  const int rhi = (lane >> 4) * 4, cix = lane & 15;
  const int first = (kbase == 0);
  float bv[4];
  #pragma unroll
  for (int n = 0; n < 4; ++n) bv[n] = b2[e * DOUT_ + n0 + wc * 64 + n * 16 + cix];
  #pragma unroll
  for (int m = 0; m < 4; ++m) {
    #pragma unroll
    for (int j = 0; j < 4; ++j) {
      int slot = row0 + wr * 64 + m * 16 + rhi + j;
      float w = wslot[slot];
      if (w == 0.f) continue;   // padding slot
      int tok = atok[slot];
      float* orow = out + (size_t)tok * DOUT_ + n0;
      #pragma unroll
      for (int n = 0; n < 4; ++n) {
        int lc = wc * 64 + n * 16 + cix;
        float v = first ? w * (acc[m][n][j] + bv[n]) : w * acc[m][n][j];
        atomicAdd(&orow[lc], v);
      }
    }
  }
}

extern "C" void kernel_launch(void* const* d_in, const int* in_sizes, int n_in,
                              void* d_out, int out_size, void* d_ws, size_t ws_size,
                              hipStream_t stream) {
  const float* x  = (const float*)d_in[0];
  const float* Wg = (const float*)d_in[1];
  const float* bg = (const float*)d_in[2];
  const float* W1 = (const float*)d_in[3];
  const float* b1 = (const float*)d_in[4];
  const float* W2 = (const float*)d_in[5];
  const float* b2 = (const float*)d_in[6];
  float* out = (float*)d_out;

  char* ws = (char*)d_ws;
  int*   counts  = (int*)(ws + 0);
  int*   cursors = (int*)(ws + 32);
  int*   offsets = (int*)(ws + 64);
  float* usage   = (float*)(ws + 128);
  int*   topi    = (int*)(ws + OFF_TOPI);
  float* topw    = (float*)(ws + OFF_TOPW);
  int*   atok    = (int*)(ws + OFF_ATOK);
  float* wslot   = (float*)(ws + OFF_WSL);
  u16*   Xg      = (u16*)(ws + OFF_XG);
  u16*   W1t     = (u16*)(ws + OFF_W1T);
  u16*   W2t     = (u16*)(ws + OFF_W2T);
  u16*   Hb      = (u16*)(ws + OFF_HB);

  k_zero_out<<<B_ * DOUT_ / 1024, 256, 0, stream>>>(out);
  k_init<<<(MAXR + 255) / 256, 256, 0, stream>>>(atok, wslot, (int*)ws);
  k_gate<<<B_ / 4, 256, 0, stream>>>(x, Wg, bg, counts, usage, topi, topw);
  k_scan_aux<<<1, 64, 0, stream>>>(counts, offsets, usage, out + (size_t)B_ * DOUT_);
  k_scatter<<<B_ / 256, 256, 0, stream>>>(topi, topw, offsets, cursors, atok, wslot);
  k_gather<<<MAXR, 256, 0, stream>>>(x, atok, Xg);
  k_cvt_t<<<dim3(D_ / 64, H_ / 64, E_), 256, 0, stream>>>(W1, W1t, D_, H_);
  k_gemm1<<<(MAXR / 128) * 16, 512, 0, stream>>>(Xg, W1t, b1, offsets, Hb);
  k_cvt_t<<<dim3(H_ / 64, DOUT_ / 64, E_), 256, 0, stream>>>(W2, W2t, H_, DOUT_);
  k_gemm2<<<dim3((MAXR / 128) * 4, 2), 512, 0, stream>>>(Hb, W2t, b2, offsets, atok, wslot, out);
}

// Round 16
// 800.558 us; speedup vs baseline: 1.2275x; 1.0223x over previous
//
#include <hip/hip_runtime.h>
#include <hip/hip_bf16.h>
#include <hip/hip_fp16.h>

#define B_    8192
#define D_    1024
#define H_    4096
#define DOUT_ 1024
#define E_    8
#define MAXR  17408   // 16384 assignments + 8*128 padding

typedef float    f32x4 __attribute__((ext_vector_type(4)));
typedef _Float16 f16x8 __attribute__((ext_vector_type(8)));
typedef unsigned short u16;
typedef u16      u16x8 __attribute__((ext_vector_type(8)));
typedef u16      u16x4 __attribute__((ext_vector_type(4)));
typedef unsigned int u32;

__device__ __forceinline__ u16 f2h_bits(float f) {
  _Float16 h = (_Float16)f;
  return __builtin_bit_cast(u16, h);
}
__device__ __forceinline__ float h2f(u16 b) {
  return (float)__builtin_bit_cast(_Float16, b);
}

// tanh-form gelu (max abs err vs erf-gelu ~3e-4; threshold margin 4x)
__device__ __forceinline__ float gelu_f(float v) {
  float z = 0.7978845608028654f * (v + 0.044715f * v * v * v);
  float ez = __expf(2.f * z);
  float th = 1.f - 2.f / (ez + 1.f);
  return 0.5f * v * (1.f + th);
}

// ---- workspace layout (bytes) ----
#define OFF_TOPI 512                       // int[16384]
#define OFF_TOPW (OFF_TOPI + 65536)        // float[16384]
#define OFF_ATOK (OFF_TOPW + 65536)        // int[17408]
#define OFF_WSL  (OFF_ATOK + 69632)        // float[17408]
#define OFF_SLOT (OFF_WSL + 69632)         // int[16384] slot_of (ends 336384)
#define OFF_XG   524288                    // u16[17408*1024] f16 (dead after gemm1)
#define OFF_W1T  (OFF_XG + 35651584)       // u16[8*4096*1024] f16 (dead after gemm1)
#define OFF_W2T  OFF_XG                    // u16[8*1024*4096], ALIASES Xg (built after gemm1)
#define OFF_Y    (OFF_XG + 67108864)       // u16[17408*1024], ALIASES W1T tail (after gemm1)
#define OFF_HB   (OFF_W1T + 67108864)      // u16[17408*4096] f16
// end = 245,891,072 bytes

__global__ void k_init(int* __restrict__ atok, float* __restrict__ wslot,
                       int* __restrict__ meta) {
  int i = blockIdx.x * 256 + threadIdx.x;
  if (i < MAXR) { atok[i] = 0; wslot[i] = 0.f; }
  if (blockIdx.x == 0 && threadIdx.x < 64) meta[threadIdx.x] = 0;
}

__global__ __launch_bounds__(256) void k_gate(
    const float* __restrict__ x, const float* __restrict__ Wg,
    const float* __restrict__ bg, int* __restrict__ counts,
    float* __restrict__ usage, int* __restrict__ topi, float* __restrict__ topw) {
  __shared__ float su[E_];
  if (threadIdx.x < E_) su[threadIdx.x] = 0.f;
  __syncthreads();
  const int lane = threadIdx.x & 63;
  const int b = blockIdx.x * 4 + (threadIdx.x >> 6);
  float p[E_] = {0.f,0.f,0.f,0.f,0.f,0.f,0.f,0.f};
  #pragma unroll
  for (int j = 0; j < 4; ++j) {
    int d = j * 256 + lane * 4;
    float4 xv = *(const float4*)&x[(size_t)b * D_ + d];
    const float* wr = &Wg[(size_t)d * E_];
    #pragma unroll
    for (int c = 0; c < 4; ++c) {
      float xc = reinterpret_cast<const float*>(&xv)[c];
      #pragma unroll
      for (int e = 0; e < E_; ++e) p[e] += xc * wr[c * E_ + e];
    }
  }
  #pragma unroll
  for (int off = 32; off >= 1; off >>= 1)
    #pragma unroll
    for (int e = 0; e < E_; ++e) p[e] += __shfl_xor(p[e], off, 64);
  float mx = -1e30f;
  #pragma unroll
  for (int e = 0; e < E_; ++e) { p[e] += bg[e]; mx = fmaxf(mx, p[e]); }
  int i0 = 0; float l0 = p[0];
  #pragma unroll
  for (int e = 1; e < E_; ++e) if (p[e] > l0) { l0 = p[e]; i0 = e; }
  int i1 = -1; float l1 = -1e30f;
  #pragma unroll
  for (int e = 0; e < E_; ++e) if (e != i0 && p[e] > l1) { l1 = p[e]; i1 = e; }
  float s = 0.f;
  #pragma unroll
  for (int e = 0; e < E_; ++e) { p[e] = expf(p[e] - mx); s += p[e]; }
  float inv = 1.f / s;
  if (lane == 0) {
    float e0 = expf(l0 - mx), e1 = expf(l1 - mx);
    float wsum = e0 + e1;
    topi[b * 2] = i0; topi[b * 2 + 1] = i1;
    topw[b * 2] = e0 / wsum; topw[b * 2 + 1] = e1 / wsum;
    atomicAdd(&counts[i0], 1);
    atomicAdd(&counts[i1], 1);
    #pragma unroll
    for (int e = 0; e < E_; ++e) atomicAdd(&su[e], p[e] * inv);
  }
  __syncthreads();
  if (threadIdx.x < E_) atomicAdd(&usage[threadIdx.x], su[threadIdx.x]);
}

__global__ void k_scan_aux(const int* __restrict__ counts, int* __restrict__ offsets,
                           const float* __restrict__ usage, float* __restrict__ auxp) {
  if (threadIdx.x == 0) {
    int off = 0;
    for (int e = 0; e < E_; ++e) { offsets[e] = off; off += (counts[e] + 127) & ~127; }
    offsets[E_] = off;
    float aux = 0.f;
    const float lu = logf(1.0f / (float)E_);
    for (int e = 0; e < E_; ++e) {
      float u = usage[e] * (1.0f / (float)B_);
      aux += u * lu - logf(u) * (1.0f / (float)E_);
    }
    *auxp = aux;
  }
}

__global__ void k_scatter(const int* __restrict__ topi, const float* __restrict__ topw,
                          const int* __restrict__ offsets, int* __restrict__ cursors,
                          int* __restrict__ atok, float* __restrict__ wslot,
                          int* __restrict__ slot_of) {
  int b = blockIdx.x * 256 + threadIdx.x;
  if (b >= B_) return;
  #pragma unroll
  for (int k = 0; k < 2; ++k) {
    int e = topi[b * 2 + k];
    int pos = atomicAdd(&cursors[e], 1);
    int slot = offsets[e] + pos;
    atok[slot] = b;
    wslot[slot] = topw[b * 2 + k];
    slot_of[b * 2 + k] = slot;
  }
}

__global__ __launch_bounds__(256) void k_gather(const float* __restrict__ x,
                                                const int* __restrict__ atok,
                                                u16* __restrict__ Xg) {
  int slot = blockIdx.x;
  int tok = atok[slot];
  int c = threadIdx.x * 4;
  float4 v = *(const float4*)&x[(size_t)tok * D_ + c];
  const float* vf = reinterpret_cast<const float*>(&v);
  u16x4 o;
  o.x = f2h_bits(vf[0]); o.y = f2h_bits(vf[1]);
  o.z = f2h_bits(vf[2]); o.w = f2h_bits(vf[3]);
  *(u16x4*)&Xg[(size_t)slot * D_ + c] = o;
}

// convert + transpose: src [E][K][N] fp32  ->  dst [E][N][K] f16. 64x64 tiles.
__global__ __launch_bounds__(256) void k_cvt_t(const float* __restrict__ src,
                                               u16* __restrict__ dst, int K, int N) {
  const int e = blockIdx.z;
  const int kt = blockIdx.x * 64;
  const int nt = blockIdx.y * 64;
  __shared__ u16 t[64][68];
  const float* s = src + (size_t)e * K * N;
  u16* d = dst + (size_t)e * N * K;
  const int tr = threadIdx.x >> 4;
  const int tc = threadIdx.x & 15;
  #pragma unroll
  for (int i = 0; i < 4; ++i) {
    int k = tr + i * 16;
    float4 v = *(const float4*)&s[(size_t)(kt + k) * N + nt + tc * 4];
    t[k][tc*4+0] = f2h_bits(v.x); t[k][tc*4+1] = f2h_bits(v.y);
    t[k][tc*4+2] = f2h_bits(v.z); t[k][tc*4+3] = f2h_bits(v.w);
  }
  __syncthreads();
  #pragma unroll
  for (int i = 0; i < 4; ++i) {
    int n = tr + i * 16;
    u16x4 o;
    o.x = t[tc*4+0][n]; o.y = t[tc*4+1][n];
    o.z = t[tc*4+2][n]; o.w = t[tc*4+3][n];
    *(u16x4*)&d[(size_t)(nt + n) * K + kt + tc * 4] = o;
  }
}

#define GLDS(g, l) __builtin_amdgcn_global_load_lds( \
    (const u32 __attribute__((address_space(1)))*)(g), \
    (u32 __attribute__((address_space(3)))*)(l), 16, 0, 0)

#define VMWAIT(N) asm volatile("s_waitcnt vmcnt(" #N ")" ::: "memory")
#define BARRIER() do { __builtin_amdgcn_s_barrier(); \
                       asm volatile("" ::: "memory"); } while (0)

// ==== 128(M)x256(N) tile, BK=32, RING-3 LDS (72KB), 8 waves (R15-proven) ====
#define NXT(x) ((x) == 24576 ? 0 : (x) + 12288)

#define STG3(LDK, kt, sb) do { \
  const int r_ = lane >> 2; \
  const int sc_ = ((lane & 3) ^ ((r_ ^ (r_ >> 2)) & 3)) * 8; \
  { \
    int rw = wid * 16 + r_; \
    GLDS(Ap + (size_t)rw * (LDK) + (kt) * 32 + sc_, SM + (sb) + wid * 512); \
  } \
  _Pragma("unroll") \
  for (int j = 0; j < 2; ++j) { \
    int seg = wid * 2 + j; \
    GLDS(Bp + (size_t)(seg * 16 + r_) * (LDK) + (kt) * 32 + sc_, \
         SM + (sb) + 4096 + seg * 512); \
  } } while (0)

#define RD_FR(rb_) do { \
  const int r15_ = lane & 15; \
  const int co_ = (((lane >> 4) ^ ((r15_ ^ (r15_ >> 2)) & 3)) * 8); \
  _Pragma("unroll") \
  for (int mi = 0; mi < 4; ++mi) \
    af[mi] = *(const f16x8*)&SM[(rb_) + (wr * 64 + mi * 16 + r15_) * 32 + co_]; \
  _Pragma("unroll") \
  for (int n = 0; n < 4; ++n) \
    bf[n] = *(const f16x8*)&SM[(rb_) + 4096 + (wc * 64 + n * 16 + r15_) * 32 + co_]; \
} while (0)

#define MM16() do { \
  __builtin_amdgcn_s_setprio(1); \
  _Pragma("unroll") \
  for (int mi = 0; mi < 4; ++mi) \
    _Pragma("unroll") \
    for (int n = 0; n < 4; ++n) \
      acc[mi][n] = __builtin_amdgcn_mfma_f32_16x16x32_f16(af[mi], bf[n], acc[mi][n], 0, 0, 0); \
  __builtin_amdgcn_s_setprio(0); \
} while (0)

#define KLOOP(LDK, NT) do { \
  int rb = 0, wb = 24576; \
  STG3(LDK, 0, 0); \
  STG3(LDK, 1, 12288); \
  VMWAIT(3); \
  BARRIER(); \
  for (int t = 0; t < (NT); ++t) { \
    RD_FR(rb); \
    if (t + 2 < (NT)) STG3(LDK, t + 2, wb); \
    BARRIER(); \
    MM16(); \
    if (t + 2 < (NT)) VMWAIT(3); \
    else if (t + 1 < (NT)) VMWAIT(0); \
    BARRIER(); \
    rb = NXT(rb); wb = NXT(wb); \
  } \
} while (0)

// GEMM1: Hb[row][n] = gelu( Xg[row][:] @ W1t[e][n][:]^T + b1[e][n] )  (f16)
__global__ __launch_bounds__(512, 4) void k_gemm1(
    const u16* __restrict__ Xg, const u16* __restrict__ W1t,
    const float* __restrict__ b1, const int* __restrict__ offsets,
    u16* __restrict__ Hb) {
  const int L = blockIdx.x;
  const int mtile = L >> 4;
  const int nt = L & 15;
  const int row0 = mtile * 128;
  if (row0 >= offsets[E_]) return;
  int e = 0;
  #pragma unroll
  for (int i = 1; i < E_; ++i) e = (row0 >= offsets[i]) ? i : e;
  const int n0 = nt * 256;
  const int tid = threadIdx.x, lane = tid & 63, wid = tid >> 6;
  const int wr = wid >> 2, wc = wid & 3;    // 2M x 4N waves, wave-tile 64x64
  __shared__ __align__(16) u16 SM[36864];   // 72 KB ring-3
  f32x4 acc[4][4] = {};
  f16x8 af[4], bf[4];
  const u16* Ap = Xg + (size_t)row0 * D_;
  const u16* Bp = W1t + (size_t)e * H_ * D_ + (size_t)n0 * D_;

  KLOOP(D_, 32);

  // epilogue: bias+gelu -> LDS (64 x 264 u16, 528B rows) -> 16B stores
  const int rhi = (lane >> 4) * 4, cix = lane & 15;
  float bv[4];
  #pragma unroll
  for (int n = 0; n < 4; ++n) bv[n] = b1[e * H_ + n0 + wc * 64 + n * 16 + cix];
  #pragma unroll
  for (int r = 0; r < 2; ++r) {
    if (wr == r) {
      #pragma unroll
      for (int m = 0; m < 4; ++m)
        #pragma unroll
        for (int n = 0; n < 4; ++n)
          #pragma unroll
          for (int j = 0; j < 4; ++j)
            SM[(m * 16 + rhi + j) * 264 + wc * 64 + n * 16 + cix] =
                f2h_bits(gelu_f(acc[m][n][j] + bv[n]));
    }
    __syncthreads();
    {
      const int rl = tid >> 3, co = (tid & 7) * 32;
      u16* dst = &Hb[(size_t)(row0 + r * 64 + rl) * H_ + n0 + co];
      const u16* srcp = &SM[rl * 264 + co];
      #pragma unroll
      for (int qq = 0; qq < 4; ++qq)
        *(u16x8*)(dst + qq * 8) = *(const u16x8*)(srcp + qq * 8);
    }
    __syncthreads();
  }
}

// GEMM2: Y[row][n] = Hb[row][:] @ W2t[e][n][:]^T + b2[e][n]   (f16, NO atomics)
// DENSE grid 136 mtiles x 4 ntiles; full K=4096 (NT=128 k-tiles of BK=32).
__global__ __launch_bounds__(512, 4) void k_gemm2(
    const u16* __restrict__ Hb, const u16* __restrict__ W2t,
    const float* __restrict__ b2, const int* __restrict__ offsets,
    u16* __restrict__ Y) {
  const int L = blockIdx.x;
  const int mtile = L >> 2;
  const int nt = L & 3;
  const int row0 = mtile * 128;
  if (row0 >= offsets[E_]) return;
  int e = 0;
  #pragma unroll
  for (int i = 1; i < E_; ++i) e = (row0 >= offsets[i]) ? i : e;
  const int n0 = nt * 256;
  const int tid = threadIdx.x, lane = tid & 63, wid = tid >> 6;
  const int wr = wid >> 2, wc = wid & 3;
  __shared__ __align__(16) u16 SM[36864];
  f32x4 acc[4][4] = {};
  f16x8 af[4], bf[4];
  const u16* Ap = Hb + (size_t)row0 * H_;
  const u16* Bp = W2t + (size_t)e * DOUT_ * H_ + (size_t)n0 * H_;

  KLOOP(H_, 128);

  // epilogue: +b2 -> LDS transpose -> coalesced 16B stores into Y (f16)
  const int rhi = (lane >> 4) * 4, cix = lane & 15;
  float bv[4];
  #pragma unroll
  for (int n = 0; n < 4; ++n) bv[n] = b2[e * DOUT_ + n0 + wc * 64 + n * 16 + cix];
  #pragma unroll
  for (int r = 0; r < 2; ++r) {
    if (wr == r) {
      #pragma unroll
      for (int m = 0; m < 4; ++m)
        #pragma unroll
        for (int n = 0; n < 4; ++n)
          #pragma unroll
          for (int j = 0; j < 4; ++j)
            SM[(m * 16 + rhi + j) * 264 + wc * 64 + n * 16 + cix] =
                f2h_bits(acc[m][n][j] + bv[n]);
    }
    __syncthreads();
    {
      const int rl = tid >> 3, co = (tid & 7) * 32;
      u16* dst = &Y[(size_t)(row0 + r * 64 + rl) * DOUT_ + n0 + co];
      const u16* srcp = &SM[rl * 264 + co];
      #pragma unroll
      for (int qq = 0; qq < 4; ++qq)
        *(u16x8*)(dst + qq * 8) = *(const u16x8*)(srcp + qq * 8);
    }
    __syncthreads();
  }
}

// combine: out[b][:] = w0 * Y[s0][:] + w1 * Y[s1][:]
__global__ __launch_bounds__(256) void k_combine(
    const u16* __restrict__ Y, const float* __restrict__ topw,
    const int* __restrict__ slot_of, float* __restrict__ out) {
  const int b = blockIdx.x;
  const int c = threadIdx.x * 4;
  const int s0 = slot_of[b * 2], s1 = slot_of[b * 2 + 1];
  const float w0 = topw[b * 2], w1 = topw[b * 2 + 1];
  u16x4 y0 = *(const u16x4*)&Y[(size_t)s0 * DOUT_ + c];
  u16x4 y1 = *(const u16x4*)&Y[(size_t)s1 * DOUT_ + c];
  float4 o;
  o.x = w0 * h2f(y0.x) + w1 * h2f(y1.x);
  o.y = w0 * h2f(y0.y) + w1 * h2f(y1.y);
  o.z = w0 * h2f(y0.z) + w1 * h2f(y1.z);
  o.w = w0 * h2f(y0.w) + w1 * h2f(y1.w);
  *(float4*)&out[(size_t)b * DOUT_ + c] = o;
}

extern "C" void kernel_launch(void* const* d_in, const int* in_sizes, int n_in,
                              void* d_out, int out_size, void* d_ws, size_t ws_size,
                              hipStream_t stream) {
  const float* x  = (const float*)d_in[0];
  const float* Wg = (const float*)d_in[1];
  const float* bg = (const float*)d_in[2];
  const float* W1 = (const float*)d_in[3];
  const float* b1 = (const float*)d_in[4];
  const float* W2 = (const float*)d_in[5];
  const float* b2 = (const float*)d_in[6];
  float* out = (float*)d_out;

  char* ws = (char*)d_ws;
  int*   counts  = (int*)(ws + 0);
  int*   cursors = (int*)(ws + 32);
  int*   offsets = (int*)(ws + 64);
  float* usage   = (float*)(ws + 128);
  int*   topi    = (int*)(ws + OFF_TOPI);
  float* topw    = (float*)(ws + OFF_TOPW);
  int*   atok    = (int*)(ws + OFF_ATOK);
  float* wslot   = (float*)(ws + OFF_WSL);
  int*   slot_of = (int*)(ws + OFF_SLOT);
  u16*   Xg      = (u16*)(ws + OFF_XG);
  u16*   W1t     = (u16*)(ws + OFF_W1T);
  u16*   W2t     = (u16*)(ws + OFF_W2T);
  u16*   Y       = (u16*)(ws + OFF_Y);
  u16*   Hb      = (u16*)(ws + OFF_HB);

  k_init<<<(MAXR + 255) / 256, 256, 0, stream>>>(atok, wslot, (int*)ws);
  k_gate<<<B_ / 4, 256, 0, stream>>>(x, Wg, bg, counts, usage, topi, topw);
  k_scan_aux<<<1, 64, 0, stream>>>(counts, offsets, usage, out + (size_t)B_ * DOUT_);
  k_scatter<<<B_ / 256, 256, 0, stream>>>(topi, topw, offsets, cursors, atok, wslot, slot_of);
  k_gather<<<MAXR, 256, 0, stream>>>(x, atok, Xg);
  k_cvt_t<<<dim3(D_ / 64, H_ / 64, E_), 256, 0, stream>>>(W1, W1t, D_, H_);
  k_gemm1<<<(MAXR / 128) * 16, 512, 0, stream>>>(Xg, W1t, b1, offsets, Hb);
  k_cvt_t<<<dim3(H_ / 64, DOUT_ / 64, E_), 256, 0, stream>>>(W2, W2t, H_, DOUT_);
  k_gemm2<<<(MAXR / 128) * 4, 512, 0, stream>>>(Hb, W2t, b2, offsets, Y);
  k_combine<<<B_, 256, 0, stream>>>(Y, topw, slot_of, out);
}